// Round 15
// baseline (425.465 us; speedup 1.0000x reference)
//
#include <hip/hip_runtime.h>
#include <stdint.h>

#define DIMN 1024
#define NH 16
#define HD 64
#define FFN 4096
#define BBATCH 2
#define SSEQ 2048
#define MROWS (BBATCH*SSEQ)   // 4096

typedef __bf16 bf16;
typedef __bf16 bf16x8 __attribute__((ext_vector_type(8)));
typedef __bf16 bf16x4 __attribute__((ext_vector_type(4)));
typedef float f32x4 __attribute__((ext_vector_type(4)));
typedef float f32x16 __attribute__((ext_vector_type(16)));
typedef uint32_t u32x4 __attribute__((ext_vector_type(4)));

#define AS1 __attribute__((address_space(1)))
#define AS3 __attribute__((address_space(3)))

__device__ __forceinline__ void gload16(const bf16* g, bf16* l) {
  __builtin_amdgcn_global_load_lds((AS1 const void*)g, (AS3 void*)l, 16, 0, 0);
}

__device__ __forceinline__ uint32_t pkbf(float a, float b) {
  union { bf16 h[2]; uint32_t u; } x;
  x.h[0] = (bf16)a; x.h[1] = (bf16)b;
  return x.u;
}

// ---------------- rope table: tab[s*64 + d] = cos, tab[s*64+32+d] = sin ----
__global__ void rope_table_kernel(float* __restrict__ tab) {
  int i = blockIdx.x * blockDim.x + threadIdx.x;   // 0..65535
  int s = i >> 5, d = i & 31;
  float invf = exp2f(-(float)d * 0.4152410118609203f);
  float fr = (float)s * invf;
  tab[s*64 + d]      = cosf(fr);
  tab[s*64 + 32 + d] = sinf(fr);
}

// ---------------- f32 -> bf16 cast (vector x4) -----------------------------
__global__ void cast_f32_bf16(const float* __restrict__ in, bf16* __restrict__ out, int n4) {
  int i = blockIdx.x * blockDim.x + threadIdx.x;
  if (i < n4) {
    f32x4 v = ((const f32x4*)in)[i];
    bf16x4 o = {(bf16)v.x, (bf16)v.y, (bf16)v.z, (bf16)v.w};
    ((bf16x4*)out)[i] = o;
  }
}

// ---------------- pack W [K][N] f32 -> MFMA fragment layout bf16 -----------
// WF[(((cb*(K/32) + kt)*4 + n)*64 + lane)*8 + j]
//   = W[kt*32 + (lane>>4)*8 + j][cb*64 + n*16 + (lane&15)]
__global__ __launch_bounds__(256) void pack_wfrag(
    const float* __restrict__ W, bf16* __restrict__ WF, int K, int N) {
  int g = blockIdx.x * 4 + (threadIdx.x >> 6);
  int l = threadIdx.x & 63;
  int KT = K >> 5;
  int n  = g & 3;
  int kt = (g >> 2) % KT;
  int cb = (g >> 2) / KT;
  int c  = cb*64 + n*16 + (l & 15);
  int k0 = kt*32 + (l >> 4)*8;
  bf16x8 v;
  #pragma unroll
  for (int j = 0; j < 8; ++j) v[j] = (bf16)W[(size_t)(k0 + j)*N + c];
  *(bf16x8*)&WF[((size_t)g*64 + l)*8] = v;
}

// ---------------- RMSNorm over (sum of NP partials + resid) ----------------
template<int NP>
__global__ __launch_bounds__(256) void rmsnorm_sum_kernel(
    const float* __restrict__ parts, const float* __restrict__ resid,
    const float* __restrict__ sc,
    float* __restrict__ outf, bf16* __restrict__ outb) {
  int row = blockIdx.x;
  int tid = threadIdx.x;
  size_t off = (size_t)row * DIMN;
  f32x4 v = ((const f32x4*)(resid + off))[tid];
  #pragma unroll
  for (int p = 0; p < NP; ++p) {
    f32x4 a = ((const f32x4*)(parts + (size_t)p * MROWS * DIMN + off))[tid];
    v.x += a.x; v.y += a.y; v.z += a.z; v.w += a.w;
  }
  float ss = v.x*v.x + v.y*v.y + v.z*v.z + v.w*v.w;
  #pragma unroll
  for (int m = 1; m < 64; m <<= 1) ss += __shfl_xor(ss, m);
  __shared__ float red[4];
  if ((tid & 63) == 0) red[tid >> 6] = ss;
  __syncthreads();
  float tot = red[0] + red[1] + red[2] + red[3];
  float inv = 1.f / (sqrtf(tot) * 0.03125f + 1e-8f);
  f32x4 s4 = ((const f32x4*)sc)[tid];
  f32x4 o = {v.x*s4.x*inv, v.y*s4.y*inv, v.z*s4.z*inv, v.w*s4.w*inv};
  if (outf) ((f32x4*)(outf + off))[tid] = o;
  if (outb) {
    bf16x4 ob = {(bf16)o.x, (bf16)o.y, (bf16)o.z, (bf16)o.w};
    ((bf16x4*)(outb + off))[tid] = ob;
  }
}

// ---------------- rw GEMM engine: 128x128 tile, 4 waves, reg-weights -------
// (r14 state: single-barrier ring-4, A swizzle -> 0 bank conflicts)
template<int EPI>
__global__ void __launch_bounds__(256, 3) gemm_rw(
    const bf16* __restrict__ A, const bf16* __restrict__ WF,
    int M, int N, int K,
    void* __restrict__ o0, void* __restrict__ o1, void* __restrict__ o2,
    const void* __restrict__ a0) {
  __shared__ __align__(16) bf16 sh_a[4*4096];
  const int tid  = threadIdx.x;
  const int lane = tid & 63;
  const int wid  = tid >> 6;

  int gx  = gridDim.x;
  int bid = blockIdx.y * gx + blockIdx.x;
  int nwg = gx * gridDim.y;
  int cpx = nwg >> 3;
  int swz = (bid & 7) * cpx + (bid >> 3);
  int bxi = swz % gx, byi = swz / gx;

  const int m0 = byi * 128, n0 = bxi * 128;
  const int wm = (wid >> 1) * 64, wn = (wid & 1) * 64;

  const int kb = blockIdx.z;
  const int KC = K / (int)gridDim.z;
  const int KT = K >> 5;           // total K-tiles in WF layout
  const int nt = KC >> 5;          // K-tiles this block processes

  const int wcb = (n0 + wn) >> 6;  // wave's 64-col block in WF
  const bf16* wf = WF + (size_t)wcb * KT * 2048;
  const bf16* a_base = A + (size_t)m0 * K + (size_t)kb * KC;

  auto stageA = [&](int kt, int buf) {
    #pragma unroll
    for (int i = 0; i < 2; ++i) {
      int idx = i*256 + tid;
      int row = idx >> 2, slot = idx & 3;
      int gch = slot ^ ((row >> 1) & 3);     // inverse-swizzled source chunk
      size_t go = (size_t)row*K + (size_t)kt*32 + gch*8;
      gload16(a_base + go, &sh_a[buf*4096 + idx*8]);   // linear LDS dest
    }
  };
  auto ldW = [&](int kta, bf16x8* bb) {
    #pragma unroll
    for (int n = 0; n < 4; ++n)
      bb[n] = *(const bf16x8*)&wf[(size_t)kta*2048 + n*512 + lane*8];
  };

  const int fr = lane & 15, fq = lane >> 4;
  const int asl = (fq ^ ((fr >> 1) & 3)) * 8;   // swizzled 16B slot for reads

  f32x4 acc[4][4] = {};
  bf16x8 bcur[4], bnxt[4];

  ldW(kb*nt, bcur);
  stageA(0, 0);
  stageA(1, 1);
  for (int t = 0; t < nt; ++t) {
    if (t + 1 < nt) {
      ldW(kb*nt + t + 1, bnxt);   // 4 VMEM
      asm volatile("s_waitcnt vmcnt(6)" ::: "memory");  // A(t)+W(t) landed
    } else {
      asm volatile("s_waitcnt vmcnt(0)" ::: "memory");
    }
    __builtin_amdgcn_sched_barrier(0);
    __builtin_amdgcn_s_barrier();        // A(t) visible to all waves
    __builtin_amdgcn_sched_barrier(0);

    const int lb = (t & 3) * 4096;
    bf16x8 af[4];
    #pragma unroll
    for (int m = 0; m < 4; ++m)
      af[m] = *(const bf16x8*)&sh_a[lb + (wm + m*16 + fr)*32 + asl];
    __builtin_amdgcn_s_setprio(1);
    #pragma unroll
    for (int m = 0; m < 4; ++m)
      #pragma unroll
      for (int n = 0; n < 4; ++n)
        acc[m][n] = __builtin_amdgcn_mfma_f32_16x16x32_bf16(af[m], bcur[n], acc[m][n], 0, 0, 0);
    __builtin_amdgcn_s_setprio(0);
    if (t + 2 < nt) stageA(t + 2, (t + 2) & 3);   // 2 VMEM (after compute)
    if (t + 1 < nt) {
      #pragma unroll
      for (int n = 0; n < 4; ++n) bcur[n] = bnxt[n];
    }
  }

  const int rq = (lane >> 4) * 4;
  const int cl = lane & 15;

  if constexpr (EPI == 0) {
    bf16* q_p = (bf16*)o0; bf16* k_p = (bf16*)o1; bf16* v_p = (bf16*)o2;
    const float* rope = (const float*)a0;
    int sec = (n0 + wn) >> 10;             // 0=q, 1=k, 2=v
    int h   = ((n0 + wn) & 1023) >> 6;
    const float qsc = (sec == 0) ? 0.18033688011112042f : 1.0f;  // 0.125*log2(e)
    #pragma unroll
    for (int m = 0; m < 4; ++m) {
      #pragma unroll
      for (int reg = 0; reg < 4; ++reg) {
        int r  = m0 + wm + m*16 + rq + reg;
        int b_ = r >> 11, s_ = r & 2047;
        int tile = s_ >> 5;
        size_t tb = ((size_t)(b_*NH + h) * 64 + tile) * 2048;  // 4KB tile base
        if (sec == 2) {
          int kvl = s_ & 31;
          int ks = kvl >> 4, hiv = (kvl >> 3) & 1, jv = kvl & 7;
          #pragma unroll
          for (int n = 0; n < 4; ++n) {
            int half = n >> 1;
            int qlv  = (n & 1) * 16 + cl;
            v_p[tb + (size_t)(ks*2 + half)*512 + (hiv*32 + qlv)*8 + jv] =
                (bf16)acc[m][n][reg];
          }
        } else {
          int qlt = s_ & 31;
          bf16* dst = (sec == 0 ? q_p : k_p);
          int lo = ((cl >> 3) * 32 + qlt) * 8 + (cl & 7);
          #pragma unroll
          for (int n = 0; n < 2; ++n) {
            int d1 = n*16 + cl;
            float c1 = rope[s_*64 + d1];
            float s1 = rope[s_*64 + 32 + d1];
            float x1 = acc[m][n][reg], x2 = acc[m][n+2][reg];
            dst[tb + (size_t)n*512 + lo]       = (bf16)((x1*c1 - x2*s1) * qsc);
            dst[tb + (size_t)(n+2)*512 + lo]   = (bf16)((x1*s1 + x2*c1) * qsc);
          }
        }
      }
    }
  } else if constexpr (EPI == 4) {
    float* op = (float*)o0 + (size_t)kb * M * N;
    #pragma unroll
    for (int m = 0; m < 4; ++m)
      #pragma unroll
      for (int n = 0; n < 4; ++n)
        #pragma unroll
        for (int reg = 0; reg < 4; ++reg) {
          int r = m0 + wm + m*16 + rq + reg;
          int c = n0 + wn + n*16 + cl;
          op[(size_t)r*N + c] = acc[m][n][reg];
        }
  }
}

// ---------------- fused FFN1: BN=64, DEEP pipeline (2 tiles in flight) -----
// 128x64 block, 4 waves, wave tile 64x32 per matrix (acc 64 AGPR).
// r15: 4 W register sets (rotation via 4x unroll, static indexing) + A-ring-4
// staged at distance 3 + steady vmcnt(12) = TWO full tiles of loads stay in
// flight across barriers (m218 counted-vmcnt; our previous vmcnt(6) was a
// 1-tile-deep drain -> documented 2-phase ceiling). Per tile t:
//   [ldW(t+2) -> vmcnt(12) -> barrier -> compute(t, buf t&3) -> stageA(t+3)]
// vmcnt(12): newest 12 = {ldW(t+2)4, stageA(t+2)2, ldW(t+1)4, stageA(t+1)2}
// -> forces A(t)+W(t) complete. Tail: vmcnt(6) at KT-2, vmcnt(0) at KT-1.
// A swizzle kept (r14, 0 conflicts). byi-fast decode kept (r10 L2 fix).
__global__ void __launch_bounds__(256, 3) gemm_ffn1_rw(
    const bf16* __restrict__ A, const bf16* __restrict__ WgF,
    const bf16* __restrict__ WlF, int M, int N, int K,
    bf16* __restrict__ o0, const float* __restrict__ bgv,
    const float* __restrict__ blv) {
  __shared__ __align__(16) bf16 sh_a[4*4096];
  const int tid  = threadIdx.x;
  const int lane = tid & 63;
  const int wid  = tid >> 6;

  int gx  = gridDim.x;                 // 64
  int bid = blockIdx.y * gx + blockIdx.x;
  int nwg = gx * gridDim.y;            // 2048, %8==0
  int cpx = nwg >> 3;
  int swz = (bid & 7) * cpx + (bid >> 3);
  int byi = swz & 31, bxi = swz >> 5;  // byi fast-varying (r10 L2 fix)

  const int m0 = byi * 128, n0 = bxi * 64;
  const int wm = (wid >> 1) * 64, wn = (wid & 1) * 32;

  const int KT = K >> 5;               // 32 K-tiles
  const int fo = wn >> 4;              // frag offset in 64-col block: 0 or 2
  const bf16* wg = WgF + (size_t)(n0 >> 6) * KT * 2048;
  const bf16* wl = WlF + (size_t)(n0 >> 6) * KT * 2048;
  const bf16* a_base = A + (size_t)m0 * K;

  auto stageA = [&](int kt, int buf) {
    #pragma unroll
    for (int i = 0; i < 2; ++i) {
      int idx = i*256 + tid;
      int row = idx >> 2, slot = idx & 3;
      int gch = slot ^ ((row >> 1) & 3);
      size_t go = (size_t)row*K + (size_t)kt*32 + gch*8;
      gload16(a_base + go, &sh_a[buf*4096 + idx*8]);
    }
  };
  auto ldW = [&](int kt, bf16x8* bb, bf16x8* cc) {
    #pragma unroll
    for (int n = 0; n < 2; ++n) {
      bb[n] = *(const bf16x8*)&wg[(size_t)kt*2048 + (fo+n)*512 + lane*8];
      cc[n] = *(const bf16x8*)&wl[(size_t)kt*2048 + (fo+n)*512 + lane*8];
    }
  };

  const int fr = lane & 15, fq = lane >> 4;
  const int asl = (fq ^ ((fr >> 1) & 3)) * 8;

  f32x4 acc[4][2] = {}, acc2[4][2] = {};
  bf16x8 wg0[2], wl0[2], wg1[2], wl1[2], wg2[2], wl2[2], wg3[2], wl3[2];

  auto compute = [&](int buf, bf16x8* bb, bf16x8* cc) {
    const int lb = buf * 4096;
    bf16x8 af[4];
    #pragma unroll
    for (int m = 0; m < 4; ++m)
      af[m] = *(const bf16x8*)&sh_a[lb + (wm + m*16 + fr)*32 + asl];
    __builtin_amdgcn_s_setprio(1);
    #pragma unroll
    for (int m = 0; m < 4; ++m)
      #pragma unroll
      for (int n = 0; n < 2; ++n) {
        acc [m][n] = __builtin_amdgcn_mfma_f32_16x16x32_bf16(af[m], bb[n], acc [m][n], 0, 0, 0);
        acc2[m][n] = __builtin_amdgcn_mfma_f32_16x16x32_bf16(af[m], cc[n], acc2[m][n], 0, 0, 0);
      }
    __builtin_amdgcn_s_setprio(0);
  };

  auto tile = [&](int t, bf16x8* curG, bf16x8* curL, bf16x8* nxtG, bf16x8* nxtL) {
    if (t + 2 < KT) {
      ldW(t + 2, nxtG, nxtL);                          // 4 VMEM
      asm volatile("s_waitcnt vmcnt(12)" ::: "memory"); // A(t)+W(t) landed
    } else if (t + 1 < KT) {
      asm volatile("s_waitcnt vmcnt(6)" ::: "memory");
    } else {
      asm volatile("s_waitcnt vmcnt(0)" ::: "memory");
    }
    __builtin_amdgcn_sched_barrier(0);
    __builtin_amdgcn_s_barrier();
    __builtin_amdgcn_sched_barrier(0);
    compute(t & 3, curG, curL);
    if (t + 3 < KT) stageA(t + 3, (t + 3) & 3);        // 2 VMEM
  };

  // prologue: W tiles 0,1 -> sets 0,1; A tiles 0,1,2 -> bufs 0,1,2 (14 ops)
  ldW(0, wg0, wl0); stageA(0, 0);
  ldW(1, wg1, wl1); stageA(1, 1);
  stageA(2, 2);

  for (int tb = 0; tb < KT; tb += 4) {
    tile(tb + 0, wg0, wl0, wg2, wl2);
    tile(tb + 1, wg1, wl1, wg3, wl3);
    tile(tb + 2, wg2, wl2, wg0, wl0);
    tile(tb + 3, wg3, wl3, wg1, wl1);
  }

  const int rq = (lane >> 4) * 4;
  const int cl = lane & 15;
  #pragma unroll
  for (int m = 0; m < 4; ++m)
    #pragma unroll
    for (int n = 0; n < 2; ++n)
      #pragma unroll
      for (int reg = 0; reg < 4; ++reg) {
        int r = m0 + wm + m*16 + rq + reg;
        int c = n0 + wn + n*16 + cl;
        float gv = acc [m][n][reg] + bgv[c];
        float lv = acc2[m][n][reg] + blv[c];
        float sg = 1.f / (1.f + __expf(-gv));
        o0[(size_t)r*N + c] = (bf16)(sg * lv);
      }
}

// ---------------- fused attention (r10 proven single-kernel form) ----------
// No-max softmax, fragment-layout inputs, double-buffered KV staging,
// counted vmcnt(2), writes AO bf16 directly (no split/combine: r12's
// KV-split was net-negative ~3.5us).
__global__ void __launch_bounds__(256) attn_kernel(
    const bf16* __restrict__ qf_g, const bf16* __restrict__ kf_g,
    const bf16* __restrict__ vf_g, bf16* __restrict__ ao_g) {
  __shared__ __align__(16) bf16 lds_k[2*2048];
  __shared__ __align__(16) bf16 lds_v[2*2048];
  const int tid  = threadIdx.x;
  const int lane = tid & 63;
  const int qw   = tid >> 6;      // wave's 32-row q group (0..3)
  const int hi   = lane >> 5;
  const int ql   = lane & 31;
  const int bh   = blockIdx.y;
  const int b_   = bh >> 4, h = bh & 15;
  const int q0   = blockIdx.x * 128 + qw * 32;
  const int qt   = blockIdx.x * 4 + qw;

  const bf16* qtile = qf_g + ((size_t)bh*64 + qt) * 2048;
  const bf16* kbase = kf_g + (size_t)bh * 64 * 2048;
  const bf16* vbase = vf_g + (size_t)bh * 64 * 2048;

  bf16x8 qf[4];
  #pragma unroll
  for (int ds = 0; ds < 4; ++ds)
    qf[ds] = *(const bf16x8*)&qtile[ds*512 + lane*8];

  f32x16 o0 = {}, o1 = {};
  float lrun = 0.f;

  gload16(kbase + tid*8, &lds_k[tid*8]);
  gload16(vbase + tid*8, &lds_v[tid*8]);

  for (int t = 0; t < 64; ++t) {
    const int cur = (t & 1) * 2048;
    if (t < 63) {
      const int nxt = 2048 - cur;
      gload16(kbase + (size_t)(t+1)*2048 + tid*8, &lds_k[nxt + tid*8]);
      gload16(vbase + (size_t)(t+1)*2048 + tid*8, &lds_v[nxt + tid*8]);
      asm volatile("s_waitcnt vmcnt(2)" ::: "memory");
    } else {
      asm volatile("s_waitcnt vmcnt(0)" ::: "memory");
    }
    __builtin_amdgcn_sched_barrier(0);
    __builtin_amdgcn_s_barrier();
    __builtin_amdgcn_sched_barrier(0);

    f32x16 st = {};
    __builtin_amdgcn_s_setprio(1);
    #pragma unroll
    for (int ds = 0; ds < 4; ++ds) {
      bf16x8 kf = *(const bf16x8*)&lds_k[cur + ds*512 + lane*8];
      st = __builtin_amdgcn_mfma_f32_32x32x16_bf16(kf, qf[ds], st, 0, 0, 0);
    }
    __builtin_amdgcn_s_setprio(0);
    float p[16];
    float psum = 0.f;
    #pragma unroll
    for (int r = 0; r < 16; ++r) { p[r] = __builtin_amdgcn_exp2f(st[r]); psum += p[r]; }
    lrun += psum;

    uint32_t w0 = pkbf(p[0],p[1]),   w1 = pkbf(p[2],p[3]);
    uint32_t w2 = pkbf(p[4],p[5]),   w3 = pkbf(p[6],p[7]);
    uint32_t w4 = pkbf(p[8],p[9]),   w5 = pkbf(p[10],p[11]);
    uint32_t w6 = pkbf(p[12],p[13]), w7 = pkbf(p[14],p[15]);
    asm("v_permlane32_swap_b32 %0, %1" : "+v"(w0), "+v"(w2));
    asm("v_permlane32_swap_b32 %0, %1" : "+v"(w1), "+v"(w3));
    asm("v_permlane32_swap_b32 %0, %1" : "+v"(w4), "+v"(w6));
    asm("v_permlane32_swap_b32 %0, %1" : "+v"(w5), "+v"(w7));

    __builtin_amdgcn_s_setprio(1);
    {
      union { u32x4 u; bf16x8 b; } pu;
      u32x4 pwa = {w0, w1, w2, w3};
      pu.u = pwa;
      bf16x8 v0 = *(const bf16x8*)&lds_v[cur + 0*512 + lane*8];
      bf16x8 v1 = *(const bf16x8*)&lds_v[cur + 1*512 + lane*8];
      o0 = __builtin_amdgcn_mfma_f32_32x32x16_bf16(v0, pu.b, o0, 0, 0, 0);
      o1 = __builtin_amdgcn_mfma_f32_32x32x16_bf16(v1, pu.b, o1, 0, 0, 0);
      u32x4 pwb = {w4, w5, w6, w7};
      pu.u = pwb;
      bf16x8 v2 = *(const bf16x8*)&lds_v[cur + 2*512 + lane*8];
      bf16x8 v3 = *(const bf16x8*)&lds_v[cur + 3*512 + lane*8];
      o0 = __builtin_amdgcn_mfma_f32_32x32x16_bf16(v2, pu.b, o0, 0, 0, 0);
      o1 = __builtin_amdgcn_mfma_f32_32x32x16_bf16(v3, pu.b, o1, 0, 0, 0);
    }
    __builtin_amdgcn_s_setprio(0);

    __builtin_amdgcn_sched_barrier(0);
    __builtin_amdgcn_s_barrier();
    __builtin_amdgcn_sched_barrier(0);
  }

  lrun += __shfl_xor(lrun, 32);
  float inv = 1.f / lrun;
  bf16* aop = ao_g + ((size_t)(b_*SSEQ) + q0 + ql) * DIMN + h*HD;
  #pragma unroll
  for (int g = 0; g < 4; ++g) {
    int dbase = 8*g + 4*hi;
    bf16x4 w0 = {(bf16)(o0[4*g]*inv), (bf16)(o0[4*g+1]*inv),
                 (bf16)(o0[4*g+2]*inv), (bf16)(o0[4*g+3]*inv)};
    *(bf16x4*)&aop[dbase] = w0;
    bf16x4 w1 = {(bf16)(o1[4*g]*inv), (bf16)(o1[4*g+1]*inv),
                 (bf16)(o1[4*g+2]*inv), (bf16)(o1[4*g+3]*inv)};
    *(bf16x4*)&aop[32 + dbase] = w1;
  }
}

// ---------------------------------------------------------------------------
// Workspace layout (bytes), max footprint 126,353,408:
//   wt   [0,        8388608)   8MB  packed W (qkv 6MB / ao 2MB / gate 8MB / ffo 8MB)
//   rope [8388608,  8912896)   0.5MB
//   xb   [8912896, 17301504)   8MB  x bf16; reused as AO after attn
//   qkv  [17301504,42467328)  24MB  QF/KF/VF fragment layouts
//   P1   [17301504,50855936)  32MB  out-proj split-2 partials (qkv dead)
//   wt2  [50855936,59244544)   8MB  WlF (during fused FFN1)
//   h1b  [84410368,92798976)   8MB  rmsnorm1 bf16 out
//   ffb  [8912896, 42467328)  32MB  swiglu out (ao/qkv/P1 dead)
//   P2   [42467328,109576192) 64MB  ff-out split-4 partials (wt2/h1b dead)
//   h1f  [109576192,126353408)16MB  rmsnorm1 f32 out (long-lived resid)
extern "C" void kernel_launch(void* const* d_in, const int* in_sizes, int n_in,
                              void* d_out, int out_size, void* d_ws, size_t ws_size,
                              hipStream_t stream) {
  const float* x      = (const float*)d_in[0];
  const float* w_qkv  = (const float*)d_in[1];
  const float* w_ao   = (const float*)d_in[2];
  const float* w_gate = (const float*)d_in[3];
  const float* b_gate = (const float*)d_in[4];
  const float* w_lin  = (const float*)d_in[5];
  const float* b_lin  = (const float*)d_in[6];
  const float* w_ffo  = (const float*)d_in[7];
  const float* scale1 = (const float*)d_in[8];
  const float* scale2 = (const float*)d_in[9];
  float* out = (float*)d_out;
  (void)ws_size; (void)in_sizes; (void)n_in; (void)out_size;

  uint8_t* ws = (uint8_t*)d_ws;
  bf16*  wt_ws   = (bf16*) (ws + 0);
  float* rope_ws = (float*)(ws + 8388608);
  bf16*  xb_ws   = (bf16*) (ws + 8912896);
  bf16*  ao_ws   = (bf16*) (ws + 8912896);    // reuse XB
  bf16*  q_ws    = (bf16*) (ws + 17301504);
  bf16*  k_ws    = (bf16*) (ws + 25690112);
  bf16*  v_ws    = (bf16*) (ws + 34078720);
  float* p1_ws   = (float*)(ws + 17301504);   // 32MB, reuse QKV region
  bf16*  wt2_ws  = (bf16*) (ws + 50855936);   // 8MB  WlF
  bf16*  h1b_ws  = (bf16*) (ws + 84410368);   // 8MB
  bf16*  ffb_ws  = (bf16*) (ws + 8912896);    // 32MB, reuse XB/AO + QKV head
  float* p2_ws   = (float*)(ws + 42467328);   // 64MB, reuse wt2/h1b + gap
  float* h1f_ws  = (float*)(ws + 109576192);  // 16MB

  // 1. rope table + x cast + pack w_qkv fragments
  rope_table_kernel<<<256, 256, 0, stream>>>(rope_ws);
  cast_f32_bf16<<<4096, 256, 0, stream>>>(x, xb_ws, MROWS*DIMN/4);
  pack_wfrag<<<1536, 256, 0, stream>>>(w_qkv, wt_ws, DIMN, 3*DIMN);
  // 2. QKV gemm (rw engine) + rope epilogue -> fragment QF/KF/VF
  gemm_rw<0><<<dim3(24, 32), 256, 0, stream>>>(xb_ws, wt_ws, MROWS, 3*DIMN, DIMN,
                                               q_ws, k_ws, v_ws, rope_ws);
  // 3. attention (single kernel, direct AO write)
  attn_kernel<<<dim3(16, 32), 256, 0, stream>>>(q_ws, k_ws, v_ws, ao_ws);
  // 4. out-proj (rw engine), split-K=2 -> f32 partials
  pack_wfrag<<<512, 256, 0, stream>>>(w_ao, wt_ws, DIMN, DIMN);
  gemm_rw<4><<<dim3(8, 32, 2), 256, 0, stream>>>(ao_ws, wt_ws, MROWS, DIMN, DIMN,
                                                 p1_ws, nullptr, nullptr, nullptr);
  // 5. rmsnorm1 over (p0+p1+x) -> f32 + bf16
  rmsnorm_sum_kernel<2><<<MROWS, 256, 0, stream>>>(p1_ws, x, scale1, h1f_ws, h1b_ws);
  // 6. fused FFN1 (BN=64, deep pipeline vmcnt(12), A-swizzle, byi-fast):
  //    sigmoid(h1b@Wg+bg) * (h1b@Wl+bl) -> bf16
  pack_wfrag<<<2048, 256, 0, stream>>>(w_gate, wt_ws, DIMN, FFN);
  pack_wfrag<<<2048, 256, 0, stream>>>(w_lin, wt2_ws, DIMN, FFN);
  gemm_ffn1_rw<<<dim3(64, 32), 256, 0, stream>>>(h1b_ws, wt_ws, wt2_ws, MROWS, FFN, DIMN,
                                                 ffb_ws, b_gate, b_lin);
  // 7. ff-out (rw engine), split-K=4 -> f32 partials
  pack_wfrag<<<2048, 256, 0, stream>>>(w_ffo, wt_ws, FFN, DIMN);
  gemm_rw<4><<<dim3(8, 32, 4), 256, 0, stream>>>(ffb_ws, wt_ws, MROWS, DIMN, FFN,
                                                 p2_ws, nullptr, nullptr, nullptr);
  // 8. rmsnorm2 over (p0+p1+p2+p3+h1f) -> output (f32)
  rmsnorm_sum_kernel<4><<<MROWS, 256, 0, stream>>>(p2_ws, h1f_ws, scale2, out, nullptr);
}

// Round 16
// 307.855 us; speedup vs baseline: 1.3820x; 1.3820x over previous
//
#include <hip/hip_runtime.h>
#include <stdint.h>

#define DIMN 1024
#define NH 16
#define HD 64
#define FFN 4096
#define BBATCH 2
#define SSEQ 2048
#define MROWS (BBATCH*SSEQ)   // 4096

typedef __bf16 bf16;
typedef __bf16 bf16x8 __attribute__((ext_vector_type(8)));
typedef __bf16 bf16x4 __attribute__((ext_vector_type(4)));
typedef float f32x4 __attribute__((ext_vector_type(4)));
typedef float f32x16 __attribute__((ext_vector_type(16)));
typedef uint32_t u32x4 __attribute__((ext_vector_type(4)));

#define AS1 __attribute__((address_space(1)))
#define AS3 __attribute__((address_space(3)))

__device__ __forceinline__ void gload16(const bf16* g, bf16* l) {
  __builtin_amdgcn_global_load_lds((AS1 const void*)g, (AS3 void*)l, 16, 0, 0);
}

__device__ __forceinline__ uint32_t pkbf(float a, float b) {
  union { bf16 h[2]; uint32_t u; } x;
  x.h[0] = (bf16)a; x.h[1] = (bf16)b;
  return x.u;
}

// ---------------- rope table: tab[s*64 + d] = cos, tab[s*64+32+d] = sin ----
__global__ void rope_table_kernel(float* __restrict__ tab) {
  int i = blockIdx.x * blockDim.x + threadIdx.x;   // 0..65535
  int s = i >> 5, d = i & 31;
  float invf = exp2f(-(float)d * 0.4152410118609203f);
  float fr = (float)s * invf;
  tab[s*64 + d]      = cosf(fr);
  tab[s*64 + 32 + d] = sinf(fr);
}

// ---------------- f32 -> bf16 cast (vector x4) -----------------------------
__global__ void cast_f32_bf16(const float* __restrict__ in, bf16* __restrict__ out, int n4) {
  int i = blockIdx.x * blockDim.x + threadIdx.x;
  if (i < n4) {
    f32x4 v = ((const f32x4*)in)[i];
    bf16x4 o = {(bf16)v.x, (bf16)v.y, (bf16)v.z, (bf16)v.w};
    ((bf16x4*)out)[i] = o;
  }
}

// ---------------- pack W [K][N] f32 -> MFMA fragment layout bf16 -----------
// WF[(((cb*(K/32) + kt)*4 + n)*64 + lane)*8 + j]
//   = W[kt*32 + (lane>>4)*8 + j][cb*64 + n*16 + (lane&15)]
__global__ __launch_bounds__(256) void pack_wfrag(
    const float* __restrict__ W, bf16* __restrict__ WF, int K, int N) {
  int g = blockIdx.x * 4 + (threadIdx.x >> 6);
  int l = threadIdx.x & 63;
  int KT = K >> 5;
  int n  = g & 3;
  int kt = (g >> 2) % KT;
  int cb = (g >> 2) / KT;
  int c  = cb*64 + n*16 + (l & 15);
  int k0 = kt*32 + (l >> 4)*8;
  bf16x8 v;
  #pragma unroll
  for (int j = 0; j < 8; ++j) v[j] = (bf16)W[(size_t)(k0 + j)*N + c];
  *(bf16x8*)&WF[((size_t)g*64 + l)*8] = v;
}

// ---------------- RMSNorm over (sum of NP partials + resid) ----------------
template<int NP>
__global__ __launch_bounds__(256) void rmsnorm_sum_kernel(
    const float* __restrict__ parts, const float* __restrict__ resid,
    const float* __restrict__ sc,
    float* __restrict__ outf, bf16* __restrict__ outb) {
  int row = blockIdx.x;
  int tid = threadIdx.x;
  size_t off = (size_t)row * DIMN;
  f32x4 v = ((const f32x4*)(resid + off))[tid];
  #pragma unroll
  for (int p = 0; p < NP; ++p) {
    f32x4 a = ((const f32x4*)(parts + (size_t)p * MROWS * DIMN + off))[tid];
    v.x += a.x; v.y += a.y; v.z += a.z; v.w += a.w;
  }
  float ss = v.x*v.x + v.y*v.y + v.z*v.z + v.w*v.w;
  #pragma unroll
  for (int m = 1; m < 64; m <<= 1) ss += __shfl_xor(ss, m);
  __shared__ float red[4];
  if ((tid & 63) == 0) red[tid >> 6] = ss;
  __syncthreads();
  float tot = red[0] + red[1] + red[2] + red[3];
  float inv = 1.f / (sqrtf(tot) * 0.03125f + 1e-8f);
  f32x4 s4 = ((const f32x4*)sc)[tid];
  f32x4 o = {v.x*s4.x*inv, v.y*s4.y*inv, v.z*s4.z*inv, v.w*s4.w*inv};
  if (outf) ((f32x4*)(outf + off))[tid] = o;
  if (outb) {
    bf16x4 ob = {(bf16)o.x, (bf16)o.y, (bf16)o.z, (bf16)o.w};
    ((bf16x4*)(outb + off))[tid] = ob;
  }
}

// ---------------- rw GEMM engine: 128x128 tile, 4 waves, reg-weights -------
// (r14 proven: single-barrier ring-4, A swizzle -> 0 bank conflicts)
template<int EPI>
__global__ void __launch_bounds__(256, 3) gemm_rw(
    const bf16* __restrict__ A, const bf16* __restrict__ WF,
    int M, int N, int K,
    void* __restrict__ o0, void* __restrict__ o1, void* __restrict__ o2,
    const void* __restrict__ a0) {
  __shared__ __align__(16) bf16 sh_a[4*4096];
  const int tid  = threadIdx.x;
  const int lane = tid & 63;
  const int wid  = tid >> 6;

  int gx  = gridDim.x;
  int bid = blockIdx.y * gx + blockIdx.x;
  int nwg = gx * gridDim.y;
  int cpx = nwg >> 3;
  int swz = (bid & 7) * cpx + (bid >> 3);
  int bxi = swz % gx, byi = swz / gx;

  const int m0 = byi * 128, n0 = bxi * 128;
  const int wm = (wid >> 1) * 64, wn = (wid & 1) * 64;

  const int kb = blockIdx.z;
  const int KC = K / (int)gridDim.z;
  const int KT = K >> 5;           // total K-tiles in WF layout
  const int nt = KC >> 5;          // K-tiles this block processes

  const int wcb = (n0 + wn) >> 6;  // wave's 64-col block in WF
  const bf16* wf = WF + (size_t)wcb * KT * 2048;
  const bf16* a_base = A + (size_t)m0 * K + (size_t)kb * KC;

  auto stageA = [&](int kt, int buf) {
    #pragma unroll
    for (int i = 0; i < 2; ++i) {
      int idx = i*256 + tid;
      int row = idx >> 2, slot = idx & 3;
      int gch = slot ^ ((row >> 1) & 3);     // inverse-swizzled source chunk
      size_t go = (size_t)row*K + (size_t)kt*32 + gch*8;
      gload16(a_base + go, &sh_a[buf*4096 + idx*8]);   // linear LDS dest
    }
  };
  auto ldW = [&](int kta, bf16x8* bb) {
    #pragma unroll
    for (int n = 0; n < 4; ++n)
      bb[n] = *(const bf16x8*)&wf[(size_t)kta*2048 + n*512 + lane*8];
  };

  const int fr = lane & 15, fq = lane >> 4;
  const int asl = (fq ^ ((fr >> 1) & 3)) * 8;   // swizzled 16B slot for reads

  f32x4 acc[4][4] = {};
  bf16x8 bcur[4], bnxt[4];

  ldW(kb*nt, bcur);
  stageA(0, 0);
  stageA(1, 1);
  for (int t = 0; t < nt; ++t) {
    if (t + 1 < nt) {
      ldW(kb*nt + t + 1, bnxt);   // 4 VMEM
      asm volatile("s_waitcnt vmcnt(6)" ::: "memory");  // A(t)+W(t) landed
    } else {
      asm volatile("s_waitcnt vmcnt(0)" ::: "memory");
    }
    __builtin_amdgcn_sched_barrier(0);
    __builtin_amdgcn_s_barrier();        // A(t) visible to all waves
    __builtin_amdgcn_sched_barrier(0);

    const int lb = (t & 3) * 4096;
    bf16x8 af[4];
    #pragma unroll
    for (int m = 0; m < 4; ++m)
      af[m] = *(const bf16x8*)&sh_a[lb + (wm + m*16 + fr)*32 + asl];
    __builtin_amdgcn_s_setprio(1);
    #pragma unroll
    for (int m = 0; m < 4; ++m)
      #pragma unroll
      for (int n = 0; n < 4; ++n)
        acc[m][n] = __builtin_amdgcn_mfma_f32_16x16x32_bf16(af[m], bcur[n], acc[m][n], 0, 0, 0);
    __builtin_amdgcn_s_setprio(0);
    if (t + 2 < nt) stageA(t + 2, (t + 2) & 3);   // 2 VMEM (after compute)
    if (t + 1 < nt) {
      #pragma unroll
      for (int n = 0; n < 4; ++n) bcur[n] = bnxt[n];
    }
  }

  const int rq = (lane >> 4) * 4;
  const int cl = lane & 15;

  if constexpr (EPI == 0) {
    bf16* q_p = (bf16*)o0; bf16* k_p = (bf16*)o1; bf16* v_p = (bf16*)o2;
    const float* rope = (const float*)a0;
    int sec = (n0 + wn) >> 10;             // 0=q, 1=k, 2=v
    int h   = ((n0 + wn) & 1023) >> 6;
    const float qsc = (sec == 0) ? 0.18033688011112042f : 1.0f;  // 0.125*log2(e)
    #pragma unroll
    for (int m = 0; m < 4; ++m) {
      #pragma unroll
      for (int reg = 0; reg < 4; ++reg) {
        int r  = m0 + wm + m*16 + rq + reg;
        int b_ = r >> 11, s_ = r & 2047;
        int tile = s_ >> 5;
        size_t tb = ((size_t)(b_*NH + h) * 64 + tile) * 2048;  // 4KB tile base
        if (sec == 2) {
          int kvl = s_ & 31;
          int ks = kvl >> 4, hiv = (kvl >> 3) & 1, jv = kvl & 7;
          #pragma unroll
          for (int n = 0; n < 4; ++n) {
            int half = n >> 1;
            int qlv  = (n & 1) * 16 + cl;
            v_p[tb + (size_t)(ks*2 + half)*512 + (hiv*32 + qlv)*8 + jv] =
                (bf16)acc[m][n][reg];
          }
        } else {
          int qlt = s_ & 31;
          bf16* dst = (sec == 0 ? q_p : k_p);
          int lo = ((cl >> 3) * 32 + qlt) * 8 + (cl & 7);
          #pragma unroll
          for (int n = 0; n < 2; ++n) {
            int d1 = n*16 + cl;
            float c1 = rope[s_*64 + d1];
            float s1 = rope[s_*64 + 32 + d1];
            float x1 = acc[m][n][reg], x2 = acc[m][n+2][reg];
            dst[tb + (size_t)n*512 + lo]       = (bf16)((x1*c1 - x2*s1) * qsc);
            dst[tb + (size_t)(n+2)*512 + lo]   = (bf16)((x1*s1 + x2*c1) * qsc);
          }
        }
      }
    }
  } else if constexpr (EPI == 4) {
    float* op = (float*)o0 + (size_t)kb * M * N;
    #pragma unroll
    for (int m = 0; m < 4; ++m)
      #pragma unroll
      for (int n = 0; n < 4; ++n)
        #pragma unroll
        for (int reg = 0; reg < 4; ++reg) {
          int r = m0 + wm + m*16 + rq + reg;
          int c = n0 + wn + n*16 + cl;
          op[(size_t)r*N + c] = acc[m][n][reg];
        }
  }
}

// ---------------- fused FFN1: BN=64, single-barrier ring-4, A-swizzle ------
// (r14 proven: 90 us, MfmaUtil 32%, 0 bank conflicts, no spill. r15's
// 2-tile-deep W pipeline spilled (WRITE 372MB) -> reverted; register budget
// at (256,3) forbids >1-tile W depth.)
// 128x64 block, 4 waves, wave tile 64x32 per matrix (acc 64 AGPR).
// byi fast-varying decode (r10): per-XCD W set 2MB L2-resident.
__global__ void __launch_bounds__(256, 3) gemm_ffn1_rw(
    const bf16* __restrict__ A, const bf16* __restrict__ WgF,
    const bf16* __restrict__ WlF, int M, int N, int K,
    bf16* __restrict__ o0, const float* __restrict__ bgv,
    const float* __restrict__ blv) {
  __shared__ __align__(16) bf16 sh_a[4*4096];
  const int tid  = threadIdx.x;
  const int lane = tid & 63;
  const int wid  = tid >> 6;

  int gx  = gridDim.x;                 // 64
  int bid = blockIdx.y * gx + blockIdx.x;
  int nwg = gx * gridDim.y;            // 2048, %8==0
  int cpx = nwg >> 3;
  int swz = (bid & 7) * cpx + (bid >> 3);
  int byi = swz & 31, bxi = swz >> 5;  // byi fast-varying (r10 L2 fix)

  const int m0 = byi * 128, n0 = bxi * 64;
  const int wm = (wid >> 1) * 64, wn = (wid & 1) * 32;

  const int KT = K >> 5;               // 32 K-tiles
  const int fo = wn >> 4;              // frag offset in 64-col block: 0 or 2
  const bf16* wg = WgF + (size_t)(n0 >> 6) * KT * 2048;
  const bf16* wl = WlF + (size_t)(n0 >> 6) * KT * 2048;
  const bf16* a_base = A + (size_t)m0 * K;

  auto stageA = [&](int kt, int buf) {
    #pragma unroll
    for (int i = 0; i < 2; ++i) {
      int idx = i*256 + tid;
      int row = idx >> 2, slot = idx & 3;
      int gch = slot ^ ((row >> 1) & 3);
      size_t go = (size_t)row*K + (size_t)kt*32 + gch*8;
      gload16(a_base + go, &sh_a[buf*4096 + idx*8]);
    }
  };
  auto ldW = [&](int kt, bf16x8* bb, bf16x8* cc) {
    #pragma unroll
    for (int n = 0; n < 2; ++n) {
      bb[n] = *(const bf16x8*)&wg[(size_t)kt*2048 + (fo+n)*512 + lane*8];
      cc[n] = *(const bf16x8*)&wl[(size_t)kt*2048 + (fo+n)*512 + lane*8];
    }
  };

  const int fr = lane & 15, fq = lane >> 4;
  const int asl = (fq ^ ((fr >> 1) & 3)) * 8;

  f32x4 acc[4][2] = {}, acc2[4][2] = {};
  bf16x8 wgA[2], wlA[2], wgB[2], wlB[2];

  auto compute = [&](int buf, bf16x8* bb, bf16x8* cc) {
    const int lb = buf * 4096;
    bf16x8 af[4];
    #pragma unroll
    for (int m = 0; m < 4; ++m)
      af[m] = *(const bf16x8*)&sh_a[lb + (wm + m*16 + fr)*32 + asl];
    __builtin_amdgcn_s_setprio(1);
    #pragma unroll
    for (int m = 0; m < 4; ++m)
      #pragma unroll
      for (int n = 0; n < 2; ++n) {
        acc [m][n] = __builtin_amdgcn_mfma_f32_16x16x32_bf16(af[m], bb[n], acc [m][n], 0, 0, 0);
        acc2[m][n] = __builtin_amdgcn_mfma_f32_16x16x32_bf16(af[m], cc[n], acc2[m][n], 0, 0, 0);
      }
    __builtin_amdgcn_s_setprio(0);
  };

  ldW(0, wgA, wlA);
  stageA(0, 0);
  stageA(1, 1);
  for (int i = 0; i < KT/2; ++i) {
    const int t0 = 2*i, t1 = 2*i + 1;
    // ---- tile t0 (regs A)
    ldW(t1, wgB, wlB);                               // 4 VMEM
    asm volatile("s_waitcnt vmcnt(6)" ::: "memory"); // A(t0)+W(t0) landed
    __builtin_amdgcn_sched_barrier(0);
    __builtin_amdgcn_s_barrier();
    __builtin_amdgcn_sched_barrier(0);
    compute(t0 & 3, wgA, wlA);
    if (t0 + 2 < KT) stageA(t0 + 2, (t0 + 2) & 3);   // 2 VMEM
    // ---- tile t1 (regs B)
    if (t1 + 1 < KT) {
      ldW(t1 + 1, wgA, wlA);
      asm volatile("s_waitcnt vmcnt(6)" ::: "memory");
    } else {
      asm volatile("s_waitcnt vmcnt(0)" ::: "memory");
    }
    __builtin_amdgcn_sched_barrier(0);
    __builtin_amdgcn_s_barrier();
    __builtin_amdgcn_sched_barrier(0);
    compute(t1 & 3, wgB, wlB);
    if (t1 + 2 < KT) stageA(t1 + 2, (t1 + 2) & 3);
  }

  const int rq = (lane >> 4) * 4;
  const int cl = lane & 15;
  #pragma unroll
  for (int m = 0; m < 4; ++m)
    #pragma unroll
    for (int n = 0; n < 2; ++n)
      #pragma unroll
      for (int reg = 0; reg < 4; ++reg) {
        int r = m0 + wm + m*16 + rq + reg;
        int c = n0 + wn + n*16 + cl;
        float gv = acc [m][n][reg] + bgv[c];
        float lv = acc2[m][n][reg] + blv[c];
        float sg = 1.f / (1.f + __expf(-gv));
        o0[(size_t)r*N + c] = (bf16)(sg * lv);
      }
}

// ---------------- fused attention (r10 proven single-kernel form) ----------
__global__ void __launch_bounds__(256) attn_kernel(
    const bf16* __restrict__ qf_g, const bf16* __restrict__ kf_g,
    const bf16* __restrict__ vf_g, bf16* __restrict__ ao_g) {
  __shared__ __align__(16) bf16 lds_k[2*2048];
  __shared__ __align__(16) bf16 lds_v[2*2048];
  const int tid  = threadIdx.x;
  const int lane = tid & 63;
  const int qw   = tid >> 6;      // wave's 32-row q group (0..3)
  const int hi   = lane >> 5;
  const int ql   = lane & 31;
  const int bh   = blockIdx.y;
  const int b_   = bh >> 4, h = bh & 15;
  const int q0   = blockIdx.x * 128 + qw * 32;
  const int qt   = blockIdx.x * 4 + qw;

  const bf16* qtile = qf_g + ((size_t)bh*64 + qt) * 2048;
  const bf16* kbase = kf_g + (size_t)bh * 64 * 2048;
  const bf16* vbase = vf_g + (size_t)bh * 64 * 2048;

  bf16x8 qf[4];
  #pragma unroll
  for (int ds = 0; ds < 4; ++ds)
    qf[ds] = *(const bf16x8*)&qtile[ds*512 + lane*8];

  f32x16 o0 = {}, o1 = {};
  float lrun = 0.f;

  gload16(kbase + tid*8, &lds_k[tid*8]);
  gload16(vbase + tid*8, &lds_v[tid*8]);

  for (int t = 0; t < 64; ++t) {
    const int cur = (t & 1) * 2048;
    if (t < 63) {
      const int nxt = 2048 - cur;
      gload16(kbase + (size_t)(t+1)*2048 + tid*8, &lds_k[nxt + tid*8]);
      gload16(vbase + (size_t)(t+1)*2048 + tid*8, &lds_v[nxt + tid*8]);
      asm volatile("s_waitcnt vmcnt(2)" ::: "memory");
    } else {
      asm volatile("s_waitcnt vmcnt(0)" ::: "memory");
    }
    __builtin_amdgcn_sched_barrier(0);
    __builtin_amdgcn_s_barrier();
    __builtin_amdgcn_sched_barrier(0);

    f32x16 st = {};
    __builtin_amdgcn_s_setprio(1);
    #pragma unroll
    for (int ds = 0; ds < 4; ++ds) {
      bf16x8 kf = *(const bf16x8*)&lds_k[cur + ds*512 + lane*8];
      st = __builtin_amdgcn_mfma_f32_32x32x16_bf16(kf, qf[ds], st, 0, 0, 0);
    }
    __builtin_amdgcn_s_setprio(0);
    float p[16];
    float psum = 0.f;
    #pragma unroll
    for (int r = 0; r < 16; ++r) { p[r] = __builtin_amdgcn_exp2f(st[r]); psum += p[r]; }
    lrun += psum;

    uint32_t w0 = pkbf(p[0],p[1]),   w1 = pkbf(p[2],p[3]);
    uint32_t w2 = pkbf(p[4],p[5]),   w3 = pkbf(p[6],p[7]);
    uint32_t w4 = pkbf(p[8],p[9]),   w5 = pkbf(p[10],p[11]);
    uint32_t w6 = pkbf(p[12],p[13]), w7 = pkbf(p[14],p[15]);
    asm("v_permlane32_swap_b32 %0, %1" : "+v"(w0), "+v"(w2));
    asm("v_permlane32_swap_b32 %0, %1" : "+v"(w1), "+v"(w3));
    asm("v_permlane32_swap_b32 %0, %1" : "+v"(w4), "+v"(w6));
    asm("v_permlane32_swap_b32 %0, %1" : "+v"(w5), "+v"(w7));

    __builtin_amdgcn_s_setprio(1);
    {
      union { u32x4 u; bf16x8 b; } pu;
      u32x4 pwa = {w0, w1, w2, w3};
      pu.u = pwa;
      bf16x8 v0 = *(const bf16x8*)&lds_v[cur + 0*512 + lane*8];
      bf16x8 v1 = *(const bf16x8*)&lds_v[cur + 1*512 + lane*8];
      o0 = __builtin_amdgcn_mfma_f32_32x32x16_bf16(v0, pu.b, o0, 0, 0, 0);
      o1 = __builtin_amdgcn_mfma_f32_32x32x16_bf16(v1, pu.b, o1, 0, 0, 0);
      u32x4 pwb = {w4, w5, w6, w7};
      pu.u = pwb;
      bf16x8 v2 = *(const bf16x8*)&lds_v[cur + 2*512 + lane*8];
      bf16x8 v3 = *(const bf16x8*)&lds_v[cur + 3*512 + lane*8];
      o0 = __builtin_amdgcn_mfma_f32_32x32x16_bf16(v2, pu.b, o0, 0, 0, 0);
      o1 = __builtin_amdgcn_mfma_f32_32x32x16_bf16(v3, pu.b, o1, 0, 0, 0);
    }
    __builtin_amdgcn_s_setprio(0);

    __builtin_amdgcn_sched_barrier(0);
    __builtin_amdgcn_s_barrier();
    __builtin_amdgcn_sched_barrier(0);
  }

  lrun += __shfl_xor(lrun, 32);
  float inv = 1.f / lrun;
  bf16* aop = ao_g + ((size_t)(b_*SSEQ) + q0 + ql) * DIMN + h*HD;
  #pragma unroll
  for (int g = 0; g < 4; ++g) {
    int dbase = 8*g + 4*hi;
    bf16x4 w0 = {(bf16)(o0[4*g]*inv), (bf16)(o0[4*g+1]*inv),
                 (bf16)(o0[4*g+2]*inv), (bf16)(o0[4*g+3]*inv)};
    *(bf16x4*)&aop[dbase] = w0;
    bf16x4 w1 = {(bf16)(o1[4*g]*inv), (bf16)(o1[4*g+1]*inv),
                 (bf16)(o1[4*g+2]*inv), (bf16)(o1[4*g+3]*inv)};
    *(bf16x4*)&aop[32 + dbase] = w1;
  }
}

// ---------------------------------------------------------------------------
// Workspace layout (bytes), max footprint 126,353,408:
//   wt   [0,        8388608)   8MB  packed W (qkv 6MB / ao 2MB / gate 8MB / ffo 8MB)
//   rope [8388608,  8912896)   0.5MB
//   xb   [8912896, 17301504)   8MB  x bf16; reused as AO after attn
//   qkv  [17301504,42467328)  24MB  QF/KF/VF fragment layouts
//   P1   [17301504,50855936)  32MB  out-proj split-2 partials (qkv dead)
//   wt2  [50855936,59244544)   8MB  WlF (during fused FFN1)
//   h1b  [84410368,92798976)   8MB  rmsnorm1 bf16 out
//   ffb  [8912896, 42467328)  32MB  swiglu out (ao/qkv/P1 dead)
//   P2   [42467328,109576192) 64MB  ff-out split-4 partials (wt2/h1b dead)
//   h1f  [109576192,126353408)16MB  rmsnorm1 f32 out (long-lived resid)
extern "C" void kernel_launch(void* const* d_in, const int* in_sizes, int n_in,
                              void* d_out, int out_size, void* d_ws, size_t ws_size,
                              hipStream_t stream) {
  const float* x      = (const float*)d_in[0];
  const float* w_qkv  = (const float*)d_in[1];
  const float* w_ao   = (const float*)d_in[2];
  const float* w_gate = (const float*)d_in[3];
  const float* b_gate = (const float*)d_in[4];
  const float* w_lin  = (const float*)d_in[5];
  const float* b_lin  = (const float*)d_in[6];
  const float* w_ffo  = (const float*)d_in[7];
  const float* scale1 = (const float*)d_in[8];
  const float* scale2 = (const float*)d_in[9];
  float* out = (float*)d_out;
  (void)ws_size; (void)in_sizes; (void)n_in; (void)out_size;

  uint8_t* ws = (uint8_t*)d_ws;
  bf16*  wt_ws   = (bf16*) (ws + 0);
  float* rope_ws = (float*)(ws + 8388608);
  bf16*  xb_ws   = (bf16*) (ws + 8912896);
  bf16*  ao_ws   = (bf16*) (ws + 8912896);    // reuse XB
  bf16*  q_ws    = (bf16*) (ws + 17301504);
  bf16*  k_ws    = (bf16*) (ws + 25690112);
  bf16*  v_ws    = (bf16*) (ws + 34078720);
  float* p1_ws   = (float*)(ws + 17301504);   // 32MB, reuse QKV region
  bf16*  wt2_ws  = (bf16*) (ws + 50855936);   // 8MB  WlF
  bf16*  h1b_ws  = (bf16*) (ws + 84410368);   // 8MB
  bf16*  ffb_ws  = (bf16*) (ws + 8912896);    // 32MB, reuse XB/AO + QKV head
  float* p2_ws   = (float*)(ws + 42467328);   // 64MB, reuse wt2/h1b + gap
  float* h1f_ws  = (float*)(ws + 109576192);  // 16MB

  // 1. rope table + x cast + pack w_qkv fragments
  rope_table_kernel<<<256, 256, 0, stream>>>(rope_ws);
  cast_f32_bf16<<<4096, 256, 0, stream>>>(x, xb_ws, MROWS*DIMN/4);
  pack_wfrag<<<1536, 256, 0, stream>>>(w_qkv, wt_ws, DIMN, 3*DIMN);
  // 2. QKV gemm (rw engine) + rope epilogue -> fragment QF/KF/VF
  gemm_rw<0><<<dim3(24, 32), 256, 0, stream>>>(xb_ws, wt_ws, MROWS, 3*DIMN, DIMN,
                                               q_ws, k_ws, v_ws, rope_ws);
  // 3. attention (single kernel, direct AO write)
  attn_kernel<<<dim3(16, 32), 256, 0, stream>>>(q_ws, k_ws, v_ws, ao_ws);
  // 4. out-proj (rw engine), split-K=2 -> f32 partials
  pack_wfrag<<<512, 256, 0, stream>>>(w_ao, wt_ws, DIMN, DIMN);
  gemm_rw<4><<<dim3(8, 32, 2), 256, 0, stream>>>(ao_ws, wt_ws, MROWS, DIMN, DIMN,
                                                 p1_ws, nullptr, nullptr, nullptr);
  // 5. rmsnorm1 over (p0+p1+x) -> f32 + bf16
  rmsnorm_sum_kernel<2><<<MROWS, 256, 0, stream>>>(p1_ws, x, scale1, h1f_ws, h1b_ws);
  // 6. fused FFN1 (BN=64, single-barrier ring-4, A-swizzle, byi-fast, r14):
  //    sigmoid(h1b@Wg+bg) * (h1b@Wl+bl) -> bf16
  pack_wfrag<<<2048, 256, 0, stream>>>(w_gate, wt_ws, DIMN, FFN);
  pack_wfrag<<<2048, 256, 0, stream>>>(w_lin, wt2_ws, DIMN, FFN);
  gemm_ffn1_rw<<<dim3(64, 32), 256, 0, stream>>>(h1b_ws, wt_ws, wt2_ws, MROWS, FFN, DIMN,
                                                 ffb_ws, b_gate, b_lin);
  // 7. ff-out (rw engine), split-K=4 -> f32 partials
  pack_wfrag<<<2048, 256, 0, stream>>>(w_ffo, wt_ws, FFN, DIMN);
  gemm_rw<4><<<dim3(8, 32, 4), 256, 0, stream>>>(ffb_ws, wt_ws, MROWS, DIMN, FFN,
                                                 p2_ws, nullptr, nullptr, nullptr);
  // 8. rmsnorm2 over (p0+p1+p2+p3+h1f) -> output (f32)
  rmsnorm_sum_kernel<4><<<MROWS, 256, 0, stream>>>(p2_ws, h1f_ws, scale2, out, nullptr);
}